// Round 11
// baseline (141.487 us; speedup 1.0000x reference)
//
#include <hip/hip_runtime.h>
#include <stdint.h>

// ---------- types ----------
typedef __attribute__((ext_vector_type(8))) __bf16 bf16x8;   // MFMA A/B frag (4 VGPRs)
typedef __attribute__((ext_vector_type(4))) float  floatx4;  // MFMA C/D frag
typedef __attribute__((ext_vector_type(4))) unsigned int uint4v;
typedef __attribute__((ext_vector_type(2))) unsigned int uint2v;
typedef __attribute__((ext_vector_type(4))) float  float4v;

__device__ __forceinline__ unsigned short f2bf(float f) {
  union { float f; unsigned int u; } x; x.f = f;
  unsigned int r = x.u + 0x7fffu + ((x.u >> 16) & 1u);  // RNE
  return (unsigned short)(r >> 16);
}

// ------ kernel 1: start/end logits + init match region with b2 (fused) -------
__global__ __launch_bounds__(256) void logits_init_kernel(
    const float* __restrict__ hidden, const float* __restrict__ w_start,
    const float* __restrict__ b_start, const float* __restrict__ w_end,
    const float* __restrict__ b_end, const float* __restrict__ b2,
    float* __restrict__ out) {
  if (blockIdx.x >= 32) {  // init part (wave-uniform branch)
    float v = b2[0];
    int idx = ((blockIdx.x - 32) * 256 + threadIdx.x) * 4;  // 128 blks -> 131072
    *(float4v*)(out + 1024 + idx) = float4v{v, v, v, v};
    return;
  }
  const int tid  = threadIdx.x;
  const int lane = tid & 63;
  const int wv   = tid >> 6;
  const int wg   = blockIdx.x * 4 + wv;

  float wsv[12], wev[12];
#pragma unroll
  for (int t = 0; t < 12; ++t) {
    wsv[t] = w_start[lane + 64 * t];
    wev[t] = w_end[lane + 64 * t];
  }
  const float bs = b_start[0];
  const float be = b_end[0];

#pragma unroll
  for (int r = 0; r < 4; ++r) {
    int row = wg * 4 + r;
    const float* h = hidden + (size_t)row * 768;
    float ps = 0.f, pe = 0.f;
#pragma unroll
    for (int t = 0; t < 12; ++t) {
      float hv = h[lane + 64 * t];
      ps += hv * wsv[t];
      pe += hv * wev[t];
    }
#pragma unroll
    for (int off = 32; off >= 1; off >>= 1) {
      ps += __shfl_xor(ps, off, 64);
      pe += __shfl_xor(pe, off, 64);
    }
    if (lane == 0) { out[row] = ps + bs; out[512 + row] = pe + be; }
  }
}

// ---------------- kernel 2: proj v3 (R8, 32x64 tiles, 768 blocks) -------------
__global__ __launch_bounds__(256) void proj_kernel(
    const float* __restrict__ hidden, const float* __restrict__ w1,
    const float* __restrict__ b1, unsigned short* __restrict__ wsR,
    unsigned short* __restrict__ wsC) {
  __shared__ short As[4 * 32 * 8];  // (q*32+row)*8+j, q = k/8 in BK=32
  __shared__ short Bs[4 * 64 * 8];  // (q*64+n  )*8+j

  const int tid  = threadIdx.x;
  const int lane = tid & 63;
  const int wave = tid >> 6;
  const int wr = wave >> 1, wc = wave & 1;
  const int m0 = blockIdx.y * 32;
  const int n0g = blockIdx.x * 64;
  const bool isR = (n0g < 1536);
  const int kbase = isR ? 0 : 768;
  const int n0 = isR ? n0g : (n0g - 1536);
  const int q = lane >> 4, l15 = lane & 15;

  floatx4 acc0 = {}, acc1 = {};

  const int a_row = tid >> 3;
  const int a_s   = tid & 7;
  const int b_n   = tid & 63;
  const int b_kg  = tid >> 6;

  const float* hrow = hidden + (size_t)(m0 + a_row) * 768 + a_s * 4;
  const float* bcol = w1 + (size_t)(kbase + b_kg * 8) * 1536 + n0 + b_n;

  float4v hv = *(const float4v*)(hrow);
  float bv[8];
#pragma unroll
  for (int a = 0; a < 8; ++a) bv[a] = bcol[(size_t)a * 1536];

  const int aq = a_s >> 1;
  const int aj = (a_s & 1) * 4;

  for (int ko = 0; ko < 768; ko += 32) {
    uint2v au;
    au[0] = (unsigned int)f2bf(hv[0]) | ((unsigned int)f2bf(hv[1]) << 16);
    au[1] = (unsigned int)f2bf(hv[2]) | ((unsigned int)f2bf(hv[3]) << 16);
    *(uint2v*)(&As[(aq * 32 + a_row) * 8 + aj]) = au;
    uint4v pv;
#pragma unroll
    for (int a = 0; a < 4; ++a) {
      unsigned int lo = f2bf(bv[2 * a]);
      unsigned int hi = f2bf(bv[2 * a + 1]);
      pv[a] = lo | (hi << 16);
    }
    *(uint4v*)(&Bs[(b_kg * 64 + b_n) * 8]) = pv;
    __syncthreads();

    if (ko + 32 < 768) {
      hv = *(const float4v*)(hrow + ko + 32);
      const float* bp = bcol + (size_t)(ko + 32) * 1536;
#pragma unroll
      for (int a = 0; a < 8; ++a) bv[a] = bp[(size_t)a * 1536];
    }

    bf16x8 af  = *(const bf16x8*)(&As[(q * 32 + 16 * wr + l15) * 8]);
    bf16x8 bg0 = *(const bf16x8*)(&Bs[(q * 64 + 32 * wc + l15) * 8]);
    bf16x8 bg1 = *(const bf16x8*)(&Bs[(q * 64 + 32 * wc + 16 + l15) * 8]);
    acc0 = __builtin_amdgcn_mfma_f32_16x16x32_bf16(af, bg0, acc0, 0, 0, 0);
    acc1 = __builtin_amdgcn_mfma_f32_16x16x32_bf16(af, bg1, acc1, 0, 0, 0);
    __syncthreads();
  }

  unsigned short* outp = isR ? wsR : wsC;
#pragma unroll
  for (int ni = 0; ni < 2; ++ni) {
    const floatx4& ac = ni ? acc1 : acc0;
    int col = n0 + 32 * wc + 16 * ni + l15;
    float bias = isR ? b1[col] : 0.0f;
#pragma unroll
    for (int r = 0; r < 4; ++r) {
      int rowg = m0 + 16 * wr + q * 4 + r;
      outp[(size_t)rowg * 1536 + col] = f2bf(ac[r] + bias);
    }
  }
}

// ---------------- kernel 3: match v6 — bf16 R/C tiles + fp32 Ws in LDS --------
// Skeleton = R4-v2 (16x16 tile, 1 output/thread, K-split x2, chunk 256).
// R/C staged as raw bf16 (1 ds_read_b128 = 8 elems; stride 264 ushorts, <=2-way
// = free); w2 chunk staged to LDS fp32 (broadcast reads, conflict-free) —
// reverts R10's scalar-load experiment (SGPR pressure caused inner-loop s_load
// stalls). LDS b128 per 8 gelu: R9=6, R10=2+8 s_loads, now 4, no s_loads.
__global__ __launch_bounds__(256) void match_kernel(
    const unsigned short* __restrict__ wsR,
    const unsigned short* __restrict__ wsC,
    const float* __restrict__ w2,
    float* __restrict__ outm) {
  __shared__ unsigned short Rs[16 * 264];
  __shared__ unsigned short Cs[16 * 264];
  __shared__ float Ws[256];

  const int tid = threadIdx.x;
  const int jt = blockIdx.x, it = blockIdx.y;
  const int bz = blockIdx.z >> 1, kh = blockIdx.z & 1;
  const int i = tid >> 4, j = tid & 15;

  constexpr float C0 = 0.39103831f;
  constexpr float C1 = -0.05415410f;
  constexpr float C2 = 0.00461682f;
  constexpr float C3 = -1.51033e-4f;

  float a0 = 0.f, a1 = 0.f, a2 = 0.f, a3 = 0.f;

  const int srow = tid >> 4;   // 0..15
  const int scc  = tid & 15;   // 16-elem chunk within 256

  for (int kc = 0; kc < 3; ++kc) {
    const int Kb = kh * 768 + kc * 256;
    {  // stage 16 rows x 256 k of R and C: raw bf16 copy (2 uint4 each) + Ws
      const unsigned short* rg = wsR + (size_t)(bz * 256 + it * 16 + srow) * 1536 + Kb + scc * 16;
      const unsigned short* cg = wsC + (size_t)(bz * 256 + jt * 16 + srow) * 1536 + Kb + scc * 16;
      uint4v rv0 = *(const uint4v*)rg;
      uint4v rv1 = *(const uint4v*)(rg + 8);
      uint4v cv0 = *(const uint4v*)cg;
      uint4v cv1 = *(const uint4v*)(cg + 8);
      unsigned short* rd = &Rs[srow * 264 + scc * 16];
      unsigned short* cd = &Cs[srow * 264 + scc * 16];
      *(uint4v*)(rd)     = rv0;
      *(uint4v*)(rd + 8) = rv1;
      *(uint4v*)(cd)     = cv0;
      *(uint4v*)(cd + 8) = cv1;
      Ws[tid] = w2[Kb + tid];
    }
    __syncthreads();

    const unsigned short* rp = &Rs[i * 264];
    const unsigned short* cp = &Cs[j * 264];
#pragma unroll 2
    for (int k = 0; k < 256; k += 8) {
      uint4v rv = *(const uint4v*)(rp + k);       // 8 bf16 of R row
      uint4v cv = *(const uint4v*)(cp + k);       // 8 bf16 of C row
      float4v w0 = *(const float4v*)(&Ws[k]);     // broadcast, conflict-free
      float4v w1v = *(const float4v*)(&Ws[k + 4]);
#pragma unroll
      for (int a = 0; a < 4; ++a) {
        union { unsigned int u; float f; } rl, rh, cl, ch;
        rl.u = rv[a] << 16; rh.u = rv[a] & 0xffff0000u;
        cl.u = cv[a] << 16; ch.u = cv[a] & 0xffff0000u;
        float w_lo = (a < 2) ? w0[2 * a]     : w1v[2 * a - 4];
        float w_hi = (a < 2) ? w0[2 * a + 1] : w1v[2 * a - 3];
        {
          float x  = rl.f + cl.f;
          float xc = fminf(fmaxf(x, -3.5f), 3.5f);
          float u  = xc * xc;
          float p  = fmaf(u, fmaf(u, fmaf(u, C3, C2), C1), C0);
          float g  = x * fmaf(xc, p, 0.5f);
          if (a == 0) a0 = fmaf(g, w_lo, a0);
          else if (a == 1) a1 = fmaf(g, w_lo, a1);
          else if (a == 2) a2 = fmaf(g, w_lo, a2);
          else a3 = fmaf(g, w_lo, a3);
        }
        {
          float x  = rh.f + ch.f;
          float xc = fminf(fmaxf(x, -3.5f), 3.5f);
          float u  = xc * xc;
          float p  = fmaf(u, fmaf(u, fmaf(u, C3, C2), C1), C0);
          float g  = x * fmaf(xc, p, 0.5f);
          if (a == 0) a0 = fmaf(g, w_hi, a0);
          else if (a == 1) a1 = fmaf(g, w_hi, a1);
          else if (a == 2) a2 = fmaf(g, w_hi, a2);
          else a3 = fmaf(g, w_hi, a3);
        }
      }
    }
    __syncthreads();
  }

  float acc = (a0 + a1) + (a2 + a3);
  size_t idx = ((size_t)bz * 256 + it * 16 + i) * 256 + (jt * 16 + j);
  unsafeAtomicAdd(&outm[idx], acc);
}

// ---------------- launch ----------------
extern "C" void kernel_launch(void* const* d_in, const int* in_sizes, int n_in,
                              void* d_out, int out_size, void* d_ws, size_t ws_size,
                              hipStream_t stream) {
  const float* hidden  = (const float*)d_in[0];
  const float* w_start = (const float*)d_in[1];
  const float* b_start = (const float*)d_in[2];
  const float* w_end   = (const float*)d_in[3];
  const float* b_end   = (const float*)d_in[4];
  const float* w1      = (const float*)d_in[5];
  const float* b1      = (const float*)d_in[6];
  const float* w2      = (const float*)d_in[7];
  const float* b2      = (const float*)d_in[8];

  float* out = (float*)d_out;
  char* ws = (char*)d_ws;
  unsigned short* wsR = (unsigned short*)(ws);             // 1,572,864 B
  unsigned short* wsC = (unsigned short*)(ws + 1572864);   // 1,572,864 B (3 MB total)

  logits_init_kernel<<<dim3(160), dim3(256), 0, stream>>>(
      hidden, w_start, b_start, w_end, b_end, b2, out);
  proj_kernel<<<dim3(48, 16), dim3(256), 0, stream>>>(hidden, w1, b1, wsR, wsC);
  match_kernel<<<dim3(16, 16, 4), dim3(256), 0, stream>>>(wsR, wsC, w2, out + 1024);
}

// Round 12
// 137.199 us; speedup vs baseline: 1.0313x; 1.0313x over previous
//
#include <hip/hip_runtime.h>
#include <stdint.h>

// ---------- types ----------
typedef __attribute__((ext_vector_type(8))) __bf16 bf16x8;   // MFMA A/B frag (4 VGPRs)
typedef __attribute__((ext_vector_type(4))) float  floatx4;  // MFMA C/D frag
typedef __attribute__((ext_vector_type(4))) unsigned int uint4v;
typedef __attribute__((ext_vector_type(2))) unsigned int uint2v;
typedef __attribute__((ext_vector_type(4))) float  float4v;

__device__ __forceinline__ unsigned short f2bf(float f) {
  union { float f; unsigned int u; } x; x.f = f;
  unsigned int r = x.u + 0x7fffu + ((x.u >> 16) & 1u);  // RNE
  return (unsigned short)(r >> 16);
}

// ------ kernel 1: start/end logits + init match region with b2 (fused) -------
__global__ __launch_bounds__(256) void logits_init_kernel(
    const float* __restrict__ hidden, const float* __restrict__ w_start,
    const float* __restrict__ b_start, const float* __restrict__ w_end,
    const float* __restrict__ b_end, const float* __restrict__ b2,
    float* __restrict__ out) {
  if (blockIdx.x >= 32) {  // init part (wave-uniform branch)
    float v = b2[0];
    int idx = ((blockIdx.x - 32) * 256 + threadIdx.x) * 4;  // 128 blks -> 131072
    *(float4v*)(out + 1024 + idx) = float4v{v, v, v, v};
    return;
  }
  const int tid  = threadIdx.x;
  const int lane = tid & 63;
  const int wv   = tid >> 6;
  const int wg   = blockIdx.x * 4 + wv;

  float wsv[12], wev[12];
#pragma unroll
  for (int t = 0; t < 12; ++t) {
    wsv[t] = w_start[lane + 64 * t];
    wev[t] = w_end[lane + 64 * t];
  }
  const float bs = b_start[0];
  const float be = b_end[0];

#pragma unroll
  for (int r = 0; r < 4; ++r) {
    int row = wg * 4 + r;
    const float* h = hidden + (size_t)row * 768;
    float ps = 0.f, pe = 0.f;
#pragma unroll
    for (int t = 0; t < 12; ++t) {
      float hv = h[lane + 64 * t];
      ps += hv * wsv[t];
      pe += hv * wev[t];
    }
#pragma unroll
    for (int off = 32; off >= 1; off >>= 1) {
      ps += __shfl_xor(ps, off, 64);
      pe += __shfl_xor(pe, off, 64);
    }
    if (lane == 0) { out[row] = ps + bs; out[512 + row] = pe + be; }
  }
}

// ---------------- kernel 2: proj v3 (R8, 32x64 tiles, 768 blocks) -------------
__global__ __launch_bounds__(256) void proj_kernel(
    const float* __restrict__ hidden, const float* __restrict__ w1,
    const float* __restrict__ b1, unsigned short* __restrict__ wsR,
    unsigned short* __restrict__ wsC) {
  __shared__ short As[4 * 32 * 8];  // (q*32+row)*8+j, q = k/8 in BK=32
  __shared__ short Bs[4 * 64 * 8];  // (q*64+n  )*8+j

  const int tid  = threadIdx.x;
  const int lane = tid & 63;
  const int wave = tid >> 6;
  const int wr = wave >> 1, wc = wave & 1;
  const int m0 = blockIdx.y * 32;
  const int n0g = blockIdx.x * 64;
  const bool isR = (n0g < 1536);
  const int kbase = isR ? 0 : 768;
  const int n0 = isR ? n0g : (n0g - 1536);
  const int q = lane >> 4, l15 = lane & 15;

  floatx4 acc0 = {}, acc1 = {};

  const int a_row = tid >> 3;
  const int a_s   = tid & 7;
  const int b_n   = tid & 63;
  const int b_kg  = tid >> 6;

  const float* hrow = hidden + (size_t)(m0 + a_row) * 768 + a_s * 4;
  const float* bcol = w1 + (size_t)(kbase + b_kg * 8) * 1536 + n0 + b_n;

  float4v hv = *(const float4v*)(hrow);
  float bv[8];
#pragma unroll
  for (int a = 0; a < 8; ++a) bv[a] = bcol[(size_t)a * 1536];

  const int aq = a_s >> 1;
  const int aj = (a_s & 1) * 4;

  for (int ko = 0; ko < 768; ko += 32) {
    uint2v au;
    au[0] = (unsigned int)f2bf(hv[0]) | ((unsigned int)f2bf(hv[1]) << 16);
    au[1] = (unsigned int)f2bf(hv[2]) | ((unsigned int)f2bf(hv[3]) << 16);
    *(uint2v*)(&As[(aq * 32 + a_row) * 8 + aj]) = au;
    uint4v pv;
#pragma unroll
    for (int a = 0; a < 4; ++a) {
      unsigned int lo = f2bf(bv[2 * a]);
      unsigned int hi = f2bf(bv[2 * a + 1]);
      pv[a] = lo | (hi << 16);
    }
    *(uint4v*)(&Bs[(b_kg * 64 + b_n) * 8]) = pv;
    __syncthreads();

    if (ko + 32 < 768) {
      hv = *(const float4v*)(hrow + ko + 32);
      const float* bp = bcol + (size_t)(ko + 32) * 1536;
#pragma unroll
      for (int a = 0; a < 8; ++a) bv[a] = bp[(size_t)a * 1536];
    }

    bf16x8 af  = *(const bf16x8*)(&As[(q * 32 + 16 * wr + l15) * 8]);
    bf16x8 bg0 = *(const bf16x8*)(&Bs[(q * 64 + 32 * wc + l15) * 8]);
    bf16x8 bg1 = *(const bf16x8*)(&Bs[(q * 64 + 32 * wc + 16 + l15) * 8]);
    acc0 = __builtin_amdgcn_mfma_f32_16x16x32_bf16(af, bg0, acc0, 0, 0, 0);
    acc1 = __builtin_amdgcn_mfma_f32_16x16x32_bf16(af, bg1, acc1, 0, 0, 0);
    __syncthreads();
  }

  unsigned short* outp = isR ? wsR : wsC;
#pragma unroll
  for (int ni = 0; ni < 2; ++ni) {
    const floatx4& ac = ni ? acc1 : acc0;
    int col = n0 + 32 * wc + 16 * ni + l15;
    float bias = isR ? b1[col] : 0.0f;
#pragma unroll
    for (int r = 0; r < 4; ++r) {
      int rowg = m0 + 16 * wr + q * 4 + r;
      outp[(size_t)rowg * 1536 + col] = f2bf(ac[r] + bias);
    }
  }
}

// ---------------- kernel 3: match v7 — fp32 tiles, 2x1 i-blocking -------------
// R9 numerics/skeleton, but each thread computes 2 output ROWS (i-blocked):
// R-row reads are LDS broadcasts (16 j-lanes same addr, conflict-free), so the
// extra R read is cheap while C and Ws reads halve per gelu: 6/8 -> 8/16 b128.
// Tile 32i x 16j, chunk 128, stride 132 (stage + c-reads <=2-way = free),
// LDS 25.8 KB. K-split x4 -> grid (16,8,8) = 1024 blocks (R9-level occupancy).
__global__ __launch_bounds__(256) void match_kernel(
    const unsigned short* __restrict__ wsR,
    const unsigned short* __restrict__ wsC,
    const float* __restrict__ w2,
    float* __restrict__ outm) {
  __shared__ float Rs[32 * 132];
  __shared__ float Cs[16 * 132];
  __shared__ float Ws[128];

  const int tid = threadIdx.x;
  const int jt = blockIdx.x, it = blockIdx.y;
  const int bz = blockIdx.z >> 2, kh = blockIdx.z & 3;
  const int i = tid >> 4, j = tid & 15;   // i: 2 rows (2i, 2i+1); j: 1 col

  constexpr float C0 = 0.39103831f;
  constexpr float C1 = -0.05415410f;
  constexpr float C2 = 0.00461682f;
  constexpr float C3 = -1.51033e-4f;

  float a00 = 0.f, a01 = 0.f, a10 = 0.f, a11 = 0.f;  // 2 rows x 2 k-phases

  // stage indices: R 32 rows x 128 k (16 elems/thread), C 16 x 128 (8/thread)
  const int rrow = tid >> 3, rko = (tid & 7) * 16;
  const int crow = tid >> 4, cko = (tid & 15) * 8;

  for (int kc = 0; kc < 3; ++kc) {
    const int Kb = kh * 384 + kc * 128;
    {  // stage: bf16 -> fp32 LDS
      const unsigned short* rg = wsR + (size_t)(bz * 256 + it * 32 + rrow) * 1536 + Kb + rko;
      const unsigned short* cg = wsC + (size_t)(bz * 256 + jt * 16 + crow) * 1536 + Kb + cko;
      uint4v rv0 = *(const uint4v*)rg;
      uint4v rv1 = *(const uint4v*)(rg + 8);
      uint4v cv  = *(const uint4v*)cg;
      float* rd = &Rs[rrow * 132 + rko];
      float* cd = &Cs[crow * 132 + cko];
      union { unsigned int u; float f; } lo, hi;
#pragma unroll
      for (int h = 0; h < 2; ++h) {
        uint4v rv = h ? rv1 : rv0;
        float4v f0, f1;
        lo.u = rv[0] << 16; hi.u = rv[0] & 0xffff0000u; f0[0] = lo.f; f0[1] = hi.f;
        lo.u = rv[1] << 16; hi.u = rv[1] & 0xffff0000u; f0[2] = lo.f; f0[3] = hi.f;
        lo.u = rv[2] << 16; hi.u = rv[2] & 0xffff0000u; f1[0] = lo.f; f1[1] = hi.f;
        lo.u = rv[3] << 16; hi.u = rv[3] & 0xffff0000u; f1[2] = lo.f; f1[3] = hi.f;
        *(float4v*)(rd + 8 * h)     = f0;
        *(float4v*)(rd + 8 * h + 4) = f1;
      }
      {
        float4v g0, g1;
        lo.u = cv[0] << 16; hi.u = cv[0] & 0xffff0000u; g0[0] = lo.f; g0[1] = hi.f;
        lo.u = cv[1] << 16; hi.u = cv[1] & 0xffff0000u; g0[2] = lo.f; g0[3] = hi.f;
        lo.u = cv[2] << 16; hi.u = cv[2] & 0xffff0000u; g1[0] = lo.f; g1[1] = hi.f;
        lo.u = cv[3] << 16; hi.u = cv[3] & 0xffff0000u; g1[2] = lo.f; g1[3] = hi.f;
        *(float4v*)(cd)     = g0;
        *(float4v*)(cd + 4) = g1;
      }
      if (tid < 128) Ws[tid] = w2[Kb + tid];
    }
    __syncthreads();

    const float* rp0 = &Rs[(2 * i) * 132];
    const float* rp1 = rp0 + 132;
    const float* cp  = &Cs[j * 132];
#pragma unroll 2
    for (int k = 0; k < 128; k += 8) {
      float4v r0a = *(const float4v*)(rp0 + k);
      float4v r0b = *(const float4v*)(rp0 + k + 4);
      float4v r1a = *(const float4v*)(rp1 + k);
      float4v r1b = *(const float4v*)(rp1 + k + 4);
      float4v ca  = *(const float4v*)(cp + k);
      float4v cb  = *(const float4v*)(cp + k + 4);
      float4v wa  = *(const float4v*)(&Ws[k]);
      float4v wb  = *(const float4v*)(&Ws[k + 4]);
#pragma unroll
      for (int d = 0; d < 4; ++d) {
        {
          float x  = r0a[d] + ca[d];
          float xc = fminf(fmaxf(x, -3.5f), 3.5f);
          float u  = xc * xc;
          float p  = fmaf(u, fmaf(u, fmaf(u, C3, C2), C1), C0);
          float g  = x * fmaf(xc, p, 0.5f);
          a00 = fmaf(g, wa[d], a00);
        }
        {
          float x  = r1a[d] + ca[d];
          float xc = fminf(fmaxf(x, -3.5f), 3.5f);
          float u  = xc * xc;
          float p  = fmaf(u, fmaf(u, fmaf(u, C3, C2), C1), C0);
          float g  = x * fmaf(xc, p, 0.5f);
          a10 = fmaf(g, wa[d], a10);
        }
        {
          float x  = r0b[d] + cb[d];
          float xc = fminf(fmaxf(x, -3.5f), 3.5f);
          float u  = xc * xc;
          float p  = fmaf(u, fmaf(u, fmaf(u, C3, C2), C1), C0);
          float g  = x * fmaf(xc, p, 0.5f);
          a01 = fmaf(g, wb[d], a01);
        }
        {
          float x  = r1b[d] + cb[d];
          float xc = fminf(fmaxf(x, -3.5f), 3.5f);
          float u  = xc * xc;
          float p  = fmaf(u, fmaf(u, fmaf(u, C3, C2), C1), C0);
          float g  = x * fmaf(xc, p, 0.5f);
          a11 = fmaf(g, wb[d], a11);
        }
      }
    }
    __syncthreads();
  }

  int gi = bz * 256 + it * 32 + 2 * i;
  int gj = jt * 16 + j;
  float* o0 = outm + (size_t)gi * 256 + gj;
  unsafeAtomicAdd(o0,       a00 + a01);
  unsafeAtomicAdd(o0 + 256, a10 + a11);
}

// ---------------- launch ----------------
extern "C" void kernel_launch(void* const* d_in, const int* in_sizes, int n_in,
                              void* d_out, int out_size, void* d_ws, size_t ws_size,
                              hipStream_t stream) {
  const float* hidden  = (const float*)d_in[0];
  const float* w_start = (const float*)d_in[1];
  const float* b_start = (const float*)d_in[2];
  const float* w_end   = (const float*)d_in[3];
  const float* b_end   = (const float*)d_in[4];
  const float* w1      = (const float*)d_in[5];
  const float* b1      = (const float*)d_in[6];
  const float* w2      = (const float*)d_in[7];
  const float* b2      = (const float*)d_in[8];

  float* out = (float*)d_out;
  char* ws = (char*)d_ws;
  unsigned short* wsR = (unsigned short*)(ws);             // 1,572,864 B
  unsigned short* wsC = (unsigned short*)(ws + 1572864);   // 1,572,864 B (3 MB total)

  logits_init_kernel<<<dim3(160), dim3(256), 0, stream>>>(
      hidden, w_start, b_start, w_end, b_end, b2, out);
  proj_kernel<<<dim3(48, 16), dim3(256), 0, stream>>>(hidden, w1, b1, wsR, wsC);
  match_kernel<<<dim3(16, 8, 8), dim3(256), 0, stream>>>(wsR, wsC, w2, out + 1024);
}